// Round 1
// baseline (423.270 us; speedup 1.0000x reference)
//
#include <hip/hip_runtime.h>

// PiecewiseLinearEmbedding: out[i,t,:] = cumsum(W, axis=1)[:, x[i,t]] + b
//   x: (8192,200) int32 in [0,128]   W: (64,129) fp32   b: (64,) fp32
//   out: (8192,200,64) fp32 = 419.4 MB  -> pure streaming-write bound.
//
// R5: nontemporal output stores.
// Decomposition of R4's 420.8 us: ~270 us is the harness's 1.678 GB arena
// poison fill (visible in rocprof top-5 at 6.2 TB/s); embed_main is the
// remainder, ~140 us. Embed's ideal traffic (419 MB W + 46 MB R) at the
// fill's own 6.2 TB/s is ~74 us -- a 2x gap that LDS/issue/occupancy math
// cannot explain (fill hits 6.2 TB/s at 10% occupancy). But if the L2 is
// write-allocating WITH fetch on our store stream, traffic doubles to
// ~885 MB = 143 us -- matching the inferred duration exactly. The fill's
// FETCH_SIZE ~ 14 KB shows full-line elision is possible on this chip;
// nt-flagged stores (__builtin_nontemporal_store -> global_store_dwordx4
// ... nt) are the HIP-level lever over TCC allocation policy.
// Everything else is byte-identical to R4 for attribution.

constexpr int F1   = 129;              // NUM_FEATURE + 1 bins
constexpr int D    = 64;               // VECTOR_DIM
constexpr int ROWS = 8192 * 200;       // 1,638,400 lookup rows
constexpr int TBL_F = F1 * D;          // 8,256 floats (33,024 B)
constexpr int TBL4  = TBL_F / 4;       // 2,064 float4

constexpr int BLOCKS = 1024;
constexpr int TPB    = 512;            // 4 blocks/CU -> 32 waves/CU (100%)
constexpr int ROWS_PER_BLOCK = ROWS / BLOCKS;          // 1600
constexpr int Q_PER_BLOCK    = ROWS_PER_BLOCK * D / 4; // 25,600 float4
constexpr int ITERS          = Q_PER_BLOCK / TPB;      // 50 exactly

typedef float floatx4 __attribute__((ext_vector_type(4)));

// Kernel 1: tbl[j*64+d] = b[d] + sum_{k<=j} W[d,k].
// W staged to LDS coalesced; 64 lanes scan; stores coalesced (256 B per j).
// NOTE: tbl stores stay temporal -- embed re-reads them from L2 immediately.
__global__ __launch_bounds__(256) void build_table_kernel(
        const float* __restrict__ W,
        const float* __restrict__ b,
        float* __restrict__ tbl) {
    __shared__ float ldsW[TBL_F];
    for (int i = threadIdx.x; i < TBL_F; i += 256)
        ldsW[i] = W[i];
    __syncthreads();
    int d = threadIdx.x;
    if (d < D) {
        float acc = b[d];
        for (int j = 0; j < F1; ++j) {
            acc += ldsW[d * F1 + j];     // bank (d+j)%32: 2-way, free
            tbl[j * D + d] = acc;        // coalesced 256 B store
        }
    }
}

// Kernel 2: stage table (33 KB) + block's 1600 x values (6.4 KB) into LDS,
// then 50 iterations of LDS-gather -> coalesced 16 B/lane streaming stores.
// Hot loop is lgkm-only; stores are fire-and-forget nontemporal.
__global__ __launch_bounds__(TPB, 8) void embed_main_kernel(
        const int* __restrict__ x,
        const float* __restrict__ tbl,
        float* __restrict__ out) {
    __shared__ floatx4 lds_tbl[TBL4];          // 33,024 B
    __shared__ int     lds_x[ROWS_PER_BLOCK];  //  6,400 B  (39,424 B total)

    const floatx4* t4 = (const floatx4*)tbl;
    for (int i = threadIdx.x; i < TBL4; i += TPB)
        lds_tbl[i] = t4[i];
    const int row0 = blockIdx.x * ROWS_PER_BLOCK;
    for (int i = threadIdx.x; i < ROWS_PER_BLOCK; i += TPB)
        lds_x[i] = x[row0 + i];
    __syncthreads();

    floatx4* out4 = (floatx4*)out + (size_t)blockIdx.x * Q_PER_BLOCK;
#pragma unroll 5
    for (int it = 0; it < ITERS; ++it) {
        int j    = it * TPB + threadIdx.x;   // block-local float4 index
        int xi   = lds_x[j >> 4];            // broadcast (16 lanes/addr)
        // word addr = xi*64 + quad*4 (+w); xi*64 % 32 == 0 -> every bank hit
        // exactly 8x per wave b128: uniform, conflict-free.
        floatx4 v = lds_tbl[xi * 16 + (j & 15)];
        __builtin_nontemporal_store(v, &out4[j]);  // wave: 1 KB contiguous nt store
    }
}

extern "C" void kernel_launch(void* const* d_in, const int* in_sizes, int n_in,
                              void* d_out, int out_size, void* d_ws, size_t ws_size,
                              hipStream_t stream) {
    const int*   x = (const int*)  d_in[0];
    const float* W = (const float*)d_in[1];
    const float* b = (const float*)d_in[2];
    float* out = (float*)d_out;
    float* tbl = (float*)d_ws;     // 33,024 B scratch; rebuilt every call

    build_table_kernel<<<1, 256, 0, stream>>>(W, b, tbl);
    embed_main_kernel<<<BLOCKS, TPB, 0, stream>>>(x, tbl, out);
}

// Round 2
// 420.266 us; speedup vs baseline: 1.0071x; 1.0071x over previous
//
#include <hip/hip_runtime.h>

// PiecewiseLinearEmbedding: out[i,t,:] = cumsum(W, axis=1)[:, x[i,t]] + b
//   x: (8192,200) int32 in [0,128]   W: (64,129) fp32   b: (64,) fp32
//   out: (8192,200,64) fp32 = 419.4 MB  -> pure streaming-write bound.
//
// R6: single fused kernel; revert nt (R5 proved it neutral -> no
// write-allocate fetch existed to elide; stores are full-line like the fill's).
// R4/R5 decomposition: dur 423 = fill ~261 (rocprof top-5) + build_table
// (1 block, 255 CUs idle, ~4-7 us) + graph gap + embed. Bottom-up embed
// should be ~75-85 us (419 MB at the fill's own 6.4 TB/s; LDS gather
// conflict-free, ~12 us of LDS pipe fully hidden at 32 waves/CU), leaving
// ~75 us of serialization/overhead suspects. This round removes every
// inter-kernel overhead: each block builds the 33 KB cumsum table itself.
//   - wave 0: per-lane row scan of W straight from global (33 KB,
//     L2-resident; 8-deep register batching -> only serial chain is
//     129 v_add_f32), writing transposed into LDS [j*64+d] (lanes span d
//     at fixed j -> banks d%32, 2-way, free).
//   - all waves: stage the block's 1600 x values first (coalesced).
//   - hot loop: byte-identical to R4 (plain stores).
// Predict dur 423 -> ~405-412; if unchanged, embed itself is ~150 us and
// the next round attacks the store-loop structure instead of overhead.

constexpr int F1   = 129;              // NUM_FEATURE + 1 bins
constexpr int D    = 64;               // VECTOR_DIM
constexpr int ROWS = 8192 * 200;       // 1,638,400 lookup rows
constexpr int TBL_F = F1 * D;          // 8,256 floats (33,024 B)
constexpr int TBL4  = TBL_F / 4;       // 2,064 float4

constexpr int BLOCKS = 1024;
constexpr int TPB    = 512;            // 4 blocks/CU -> 32 waves/CU (100%)
constexpr int ROWS_PER_BLOCK = ROWS / BLOCKS;          // 1600
constexpr int Q_PER_BLOCK    = ROWS_PER_BLOCK * D / 4; // 25,600 float4
constexpr int ITERS          = Q_PER_BLOCK / TPB;      // 50 exactly

typedef float floatx4 __attribute__((ext_vector_type(4)));

__global__ __launch_bounds__(TPB, 8) void embed_fused_kernel(
        const int*   __restrict__ x,
        const float* __restrict__ W,
        const float* __restrict__ b,
        float*       __restrict__ out) {
    __shared__ floatx4 lds_tbl[TBL4];          // 33,024 B, final j-major table
    __shared__ int     lds_x[ROWS_PER_BLOCK];  //  6,400 B  (39,424 B total -> 4 blk/CU)
    float* tblf = (float*)lds_tbl;

    // All waves: stage this block's x slice (coalesced, 4 rounds).
    const int row0 = blockIdx.x * ROWS_PER_BLOCK;
    for (int i = threadIdx.x; i < ROWS_PER_BLOCK; i += TPB)
        lds_x[i] = x[row0 + i];

    // Wave 0: build the table. Lane d scans W row d from global (L2-hot
    // 33 KB). Loads batched 8-deep so the only dependent chain is the adds.
    // LDS writes [j*64+d]: within an instr lanes span d at fixed j ->
    // bank d%32, 2-way, conflict-free.
    if (threadIdx.x < D) {
        const int d = threadIdx.x;
        const float* wrow = W + d * F1;
        float acc = b[d];
        int j = 0;
#pragma unroll 1
        for (int c = 0; c < 16; ++c) {         // 16 chunks of 8 = 128
            float v[8];
#pragma unroll
            for (int i = 0; i < 8; ++i) v[i] = wrow[j + i];   // independent loads
#pragma unroll
            for (int i = 0; i < 8; ++i) { acc += v[i]; tblf[(j + i) * D + d] = acc; }
            j += 8;
        }
        acc += wrow[128];                      // tail bin
        tblf[128 * D + d] = acc;
    }
    __syncthreads();

    // Hot loop: LDS gather -> coalesced 16 B/lane streaming stores.
    floatx4* out4 = (floatx4*)out + (size_t)blockIdx.x * Q_PER_BLOCK;
#pragma unroll 5
    for (int it = 0; it < ITERS; ++it) {
        int j    = it * TPB + threadIdx.x;   // block-local float4 index
        int xi   = lds_x[j >> 4];            // broadcast (16 lanes/addr)
        // word addr = xi*64 + quad*4 (+w); xi*64 % 32 == 0 -> every bank hit
        // exactly 8x per wave b128: uniform, conflict-free.
        floatx4 v = lds_tbl[xi * 16 + (j & 15)];
        out4[j] = v;                         // wave: 1 KB contiguous store
    }
}

extern "C" void kernel_launch(void* const* d_in, const int* in_sizes, int n_in,
                              void* d_out, int out_size, void* d_ws, size_t ws_size,
                              hipStream_t stream) {
    const int*   x = (const int*)  d_in[0];
    const float* W = (const float*)d_in[1];
    const float* b = (const float*)d_in[2];
    float* out = (float*)d_out;
    (void)d_ws; (void)ws_size;               // no workspace needed anymore

    embed_fused_kernel<<<BLOCKS, TPB, 0, stream>>>(x, W, b, out);
}

// Round 3
// 412.928 us; speedup vs baseline: 1.0250x; 1.0178x over previous
//
#include <hip/hip_runtime.h>

// PiecewiseLinearEmbedding: out[i,t,:] = cumsum(W, axis=1)[:, x[i,t]] + b
//   x: (8192,200) int32 in [0,128]   W: (64,129) fp32   b: (64,) fp32
//   out: (8192,200,64) fp32 = 419.4 MB  -> pure streaming-write bound.
//
// R7: grid-stride store sweep (mimic fillBuffer's address schedule).
// Evidence chain: R5 (nt stores) neutral -> no write-allocate fetch.
// R6 (fusion) -3 us -> launch/build overhead ~3 us; embed itself ~147 us
// = 2.85 TB/s stores vs the fill's 6.4 TB/s on the SAME arena. LDS,
// occupancy, store-instruction shape all cleared by arithmetic; the one
// structural difference is the global address schedule:
//   fill: grid-strided -> instantaneous store window is one dense sweep,
//         uniform over HBM channels.
//   ours (R4-R6): 1024 block-partitioned streams at 409,600 B = 100*4KB
//         spacing -> at 4 KB channel interleave, near-lockstep blocks sit
//         on channel (4i+t) mod 32: only 8 of 32 channels per phase.
//         Correlated channel camping ~= the observed 2x BW loss.
// This round: iteration it stores the dense 8 MB window
//   q = it*G + blockIdx.x*TPB + tid   (G = BLOCKS*TPB = 2^19 float4s).
// x-staging re-indexed to match (50 chunks of 32 rows at 32768-row
// stride, still prestaged + coalesced). Everything else identical to R6.
// Predict: embed 147 -> ~70-80 us, dur 420 -> ~345-355. If unchanged,
// camping refuted -> next round A/Bs a table-free pure-store kernel.

constexpr int F1   = 129;              // NUM_FEATURE + 1 bins
constexpr int D    = 64;               // VECTOR_DIM
constexpr int ROWS = 8192 * 200;       // 1,638,400 lookup rows
constexpr int TBL_F = F1 * D;          // 8,256 floats (33,024 B)
constexpr int TBL4  = TBL_F / 4;       // 2,064 float4

constexpr int BLOCKS = 1024;
constexpr int TPB    = 512;            // 4 blocks/CU -> 32 waves/CU (100%)
constexpr int G      = BLOCKS * TPB;   // 524,288 threads = 2^19
constexpr int Q_TOT  = ROWS * D / 4;   // 26,214,400 float4 total
constexpr int ITERS  = Q_TOT / G;      // 50 exactly
constexpr int ROWS_PER_BLOCK = ROWS / BLOCKS;   // 1600 (50 chunks x 32 rows)
constexpr int ROWS_PER_ITER  = G / 16;          // 32,768 rows per sweep window

typedef float floatx4 __attribute__((ext_vector_type(4)));

__global__ __launch_bounds__(TPB, 8) void embed_fused_kernel(
        const int*   __restrict__ x,
        const float* __restrict__ W,
        const float* __restrict__ b,
        float*       __restrict__ out) {
    __shared__ floatx4 lds_tbl[TBL4];          // 33,024 B, j-major table
    __shared__ int     lds_x[ROWS_PER_BLOCK];  //  6,400 B  (39,424 B -> 4 blk/CU)
    float* tblf = (float*)lds_tbl;

    // Stage this block's 50 x-chunks (32 consecutive rows each, at
    // 32,768-row stride): lds_x[it*32 + r] = x[it*32768 + blockIdx.x*32 + r].
    // Per 32-element chunk the global read is a contiguous 128 B segment.
    const int xbase = blockIdx.x * 32;
    for (int i = threadIdx.x; i < ROWS_PER_BLOCK; i += TPB)
        lds_x[i] = x[(i >> 5) * ROWS_PER_ITER + xbase + (i & 31)];

    // Wave 0: build the cumsum table. Lane d scans W row d from global
    // (L2-hot 33 KB); loads batched 8-deep so the only serial chain is
    // 129 v_add_f32. LDS writes [j*64+d]: lanes span d at fixed j ->
    // bank d%32, 2-way, conflict-free.
    if (threadIdx.x < D) {
        const int d = threadIdx.x;
        const float* wrow = W + d * F1;
        float acc = b[d];
        int j = 0;
#pragma unroll 1
        for (int c = 0; c < 16; ++c) {         // 16 chunks of 8 = 128
            float v[8];
#pragma unroll
            for (int i = 0; i < 8; ++i) v[i] = wrow[j + i];   // independent loads
#pragma unroll
            for (int i = 0; i < 8; ++i) { acc += v[i]; tblf[(j + i) * D + d] = acc; }
            j += 8;
        }
        acc += wrow[128];                      // tail bin
        tblf[128 * D + d] = acc;
    }
    __syncthreads();

    // Hot loop: grid-stride dense sweep. Iteration it: whole device writes
    // the contiguous 8 MB window [it*G, (it+1)*G) of float4s.
    //   q>>4  = it*32768 + blockIdx.x*32 + (tid>>4)  -> lds_x[it*32+(tid>>4)]
    //   q&15  = tid&15                                (G, blk offs mult of 16)
    // Gather: 16 lanes/addr broadcast on lds_x; lds_tbl b128 read uniform
    // over banks (xi*64 words % 32 == 0), conflict-free as before.
    floatx4* out4 = (floatx4*)out;
    const int base = blockIdx.x * TPB + threadIdx.x;
    const int xrow = threadIdx.x >> 4;
    const int quad = threadIdx.x & 15;
#pragma unroll 5
    for (int it = 0; it < ITERS; ++it) {
        int q  = it * G + base;              // < 2^25, int-safe
        int xi = lds_x[it * 32 + xrow];      // broadcast (16 lanes/addr)
        floatx4 v = lds_tbl[xi * 16 + quad];
        out4[q] = v;                         // wave: 1 KB contiguous store
    }
}

extern "C" void kernel_launch(void* const* d_in, const int* in_sizes, int n_in,
                              void* d_out, int out_size, void* d_ws, size_t ws_size,
                              hipStream_t stream) {
    const int*   x = (const int*)  d_in[0];
    const float* W = (const float*)d_in[1];
    const float* b = (const float*)d_in[2];
    float* out = (float*)d_out;
    (void)d_ws; (void)ws_size;

    embed_fused_kernel<<<BLOCKS, TPB, 0, stream>>>(x, W, b, out);
}